// Round 7
// baseline (1372.194 us; speedup 1.0000x reference)
//
#include <hip/hip_runtime.h>

#define IN_F    2048
#define OUT_F   2048
#define BKW     64      // mask window (k-block)
#define BSTAGE  32      // k columns staged per stage (half a mask block)
#define BM      256
#define BN      64
#define NKB     32      // IN_F / BKW
#define NOB     32      // OUT_F / BN
#define THREADS 256

typedef __attribute__((address_space(3))) void lds_void_t;
typedef const __attribute__((address_space(1))) void gbl_void_t;

// Block-sparse masked linear: y = x @ (mask*W)^T + b.
// 64x64 block-constant mask -> detect nonzero k-blocks via corner sample.
// 40KB LDS (3-4 blocks/CU). x staged global->LDS direct (width-16 gload_lds,
// pre-swizzled global source, linear LDS dest). w*mask staged via regs,
// software-pipelined. All ds_read_b128 conflict-free via XOR chunk swizzle.
__global__ __launch_bounds__(THREADS, 3)
void rl_sparse_v2(const float* __restrict__ x,
                  const float* __restrict__ w,
                  const float* __restrict__ mask,
                  const float* __restrict__ bias,
                  float* __restrict__ out)
{
    __shared__ __align__(16) float xs[BM * BSTAGE];    // 32KB; phys chunk = c ^ ((row>>3)&7)
    __shared__ __align__(16) float wsb[BN * BSTAGE];   // 8KB;  phys chunk = c ^ ((row>>2)&7)

    const int tid = threadIdx.x;
    const int ob  = blockIdx.x & (NOB - 1);
    const int mt  = blockIdx.x >> 5;
    const size_t m_base = (size_t)mt * BM;
    const int n_base = ob * BN;

    // nonzero k-block bitmask (uniform across all waves)
    const int lane = tid & 63;
    float mvs = 0.0f;
    if (lane < NKB) mvs = mask[(size_t)n_base * IN_F + (size_t)lane * BKW];
    unsigned long long rem = __ballot(mvs != 0.0f);

    // compute-phase mapping: thread tile 8m x 8n; cols {tn*4..+3, 32+tn*4..+3}
    const int tn = tid & 7;
    const int tm = tid >> 3;

    // x gload_lds mapping
    const int gl_wave = tid >> 6;
    const int gl_l    = tid & 63;

    // w/mask staging mapping: thread -> (row, two chunks)
    const int wrow = tid >> 2;          // 0..63
    const int wc0  = tid & 3;           // chunks wc0 and wc0+4
    const int selw_st = (wrow >> 2) & 7;

    float acc[8][8];
    #pragma unroll
    for (int i = 0; i < 8; ++i)
        #pragma unroll
        for (int j = 0; j < 8; ++j) acc[i][j] = 0.0f;

    int cur_kb = rem ? (__ffsll(rem) - 1) : -1;
    int cur_half = 0;

    float4 wra, wrb, mra, mrb;
    if (cur_kb >= 0) {
        const size_t kc0 = (size_t)cur_kb * BKW;
        const float* wp = w    + (size_t)(n_base + wrow) * IN_F + kc0;
        const float* mp = mask + (size_t)(n_base + wrow) * IN_F + kc0;
        wra = *(const float4*)(wp + wc0 * 4);
        wrb = *(const float4*)(wp + (wc0 + 4) * 4);
        mra = *(const float4*)(mp + wc0 * 4);
        mrb = *(const float4*)(mp + (wc0 + 4) * 4);
    }

    while (cur_kb >= 0) {
        const size_t kcol = (size_t)cur_kb * BKW + (size_t)cur_half * BSTAGE;

        // advance stage bookkeeping
        unsigned long long nrem = rem;
        int nxt_kb = cur_kb, nxt_half = cur_half + 1;
        if (nxt_half == 2) {
            nrem &= (nrem - 1);
            nxt_half = 0;
            nxt_kb = nrem ? (__ffsll(nrem) - 1) : -1;
        }

        __syncthreads();   // all waves done reading previous tiles

        // ---- x: global -> LDS direct, linear dest, source pre-swizzled ----
        // instr I covers rows [gl_wave*64 + I*8, +8); per lane: row += l>>3,
        // source chunk = (l&7) ^ I  (since sel(row) = (row>>3)&7 = I here)
        #pragma unroll
        for (int I = 0; I < 8; ++I) {
            const int row = gl_wave * 64 + I * 8 + (gl_l >> 3);
            const int cch = (gl_l & 7) ^ I;
            const float* src = x + (m_base + row) * (size_t)IN_F + kcol + cch * 4;
            __builtin_amdgcn_global_load_lds((gbl_void_t*)src,
                                             (lds_void_t*)&xs[(gl_wave * 64 + I * 8) * BSTAGE],
                                             16, 0, 0);
        }

        // ---- w_eff = w*mask from prefetched regs -> LDS (swizzled write) ----
        float4 va, vb;
        va.x = wra.x * mra.x; va.y = wra.y * mra.y; va.z = wra.z * mra.z; va.w = wra.w * mra.w;
        vb.x = wrb.x * mrb.x; vb.y = wrb.y * mrb.y; vb.z = wrb.z * mrb.z; vb.w = wrb.w * mrb.w;

        // prefetch next stage's w/mask (issued before the draining barrier so
        // latency overlaps the gload_lds wait; regs consumed above already)
        if (nxt_kb >= 0) {
            const size_t nk = (size_t)nxt_kb * BKW + (size_t)nxt_half * BSTAGE;
            const float* wp = w    + (size_t)(n_base + wrow) * IN_F + nk;
            const float* mp = mask + (size_t)(n_base + wrow) * IN_F + nk;
            wra = *(const float4*)(wp + wc0 * 4);
            wrb = *(const float4*)(wp + (wc0 + 4) * 4);
            mra = *(const float4*)(mp + wc0 * 4);
            mrb = *(const float4*)(mp + (wc0 + 4) * 4);
        }

        *(float4*)(&wsb[wrow * BSTAGE + ((wc0 ^ selw_st) << 2)])       = va;
        *(float4*)(&wsb[wrow * BSTAGE + (((wc0 + 4) ^ selw_st) << 2)]) = vb;

        __syncthreads();   // drains vmcnt(0)+lgkmcnt(0): x in LDS, wsb written

        // ---- compute: 8 chunks of 4k; 16 conflict-free ds_read_b128 + 256 FMA ----
        const float* xrow = &xs[tm * 8 * BSTAGE];
        #pragma unroll 4
        for (int kc = 0; kc < 8; ++kc) {
            const int offx = ((kc ^ (tm & 7)) << 2);
            const int offw = ((kc ^ tn) << 2);
            float4 xv[8], wv[8];
            #pragma unroll
            for (int i = 0; i < 8; ++i)
                xv[i] = *(const float4*)(xrow + i * BSTAGE + offx);
            #pragma unroll
            for (int j = 0; j < 4; ++j)
                wv[j] = *(const float4*)(&wsb[(tn * 4 + j) * BSTAGE + offw]);
            #pragma unroll
            for (int j = 0; j < 4; ++j)
                wv[4 + j] = *(const float4*)(&wsb[(32 + tn * 4 + j) * BSTAGE + offw]);
            #pragma unroll
            for (int i = 0; i < 8; ++i)
                #pragma unroll
                for (int j = 0; j < 8; ++j) {
                    acc[i][j] += xv[i].x * wv[j].x;
                    acc[i][j] += xv[i].y * wv[j].y;
                    acc[i][j] += xv[i].z * wv[j].z;
                    acc[i][j] += xv[i].w * wv[j].w;
                }
        }

        cur_kb = nxt_kb; cur_half = nxt_half; rem = nrem;
    }

    // ---- epilogue: +bias, full-128B-line stores ----
    // store0: cols [tn*4, +4)   -> lanes 0..7 cover bytes 0..127 of a row
    // store1: cols [32+tn*4,+4) -> bytes 128..255
    const float4 b0 = *(const float4*)(bias + n_base + tn * 4);
    const float4 b1 = *(const float4*)(bias + n_base + 32 + tn * 4);
    #pragma unroll
    for (int i = 0; i < 8; ++i) {
        const size_t row = m_base + tm * 8 + i;
        float* op = out + row * OUT_F + n_base;
        float4 o0 = make_float4(acc[i][0] + b0.x, acc[i][1] + b0.y,
                                acc[i][2] + b0.z, acc[i][3] + b0.w);
        float4 o1 = make_float4(acc[i][4] + b1.x, acc[i][5] + b1.y,
                                acc[i][6] + b1.z, acc[i][7] + b1.w);
        *(float4*)(op + tn * 4)      = o0;
        *(float4*)(op + 32 + tn * 4) = o1;
    }
}

extern "C" void kernel_launch(void* const* d_in, const int* in_sizes, int n_in,
                              void* d_out, int out_size, void* d_ws, size_t ws_size,
                              hipStream_t stream) {
    const float* x    = (const float*)d_in[0];
    const float* w    = (const float*)d_in[1];
    const float* mask = (const float*)d_in[2];
    const float* bias = (const float*)d_in[3];
    float* out = (float*)d_out;

    const int M = in_sizes[0] / IN_F;          // 32768
    dim3 grid((M / BM) * NOB);                 // 128 m-tiles * 32 o-blocks = 4096
    rl_sparse_v2<<<grid, THREADS, 0, stream>>>(x, w, mask, bias, out);
}